// Round 20
// baseline (126.762 us; speedup 1.0000x reference)
//
#include <hip/hip_runtime.h>
#include <hip/hip_bf16.h>
#include <stdint.h>

#define B_DIM 8
#define S_LEN 2048
#define DMODEL 2048
#define HDIM 128

typedef __attribute__((ext_vector_type(4))) float f32x4;
typedef __attribute__((ext_vector_type(8))) short bf16x8;
typedef __attribute__((ext_vector_type(4))) short bf16x4;
typedef __attribute__((ext_vector_type(4))) unsigned int u32x4;
typedef unsigned short u16;
typedef unsigned int u32;

__device__ __forceinline__ u16 f2bf(float f) {
    union { float f; u32 u; } v; v.f = f;
    u32 u = v.u;
    u32 r = (u + 0x7fffu + ((u >> 16) & 1u)) >> 16;
    return (u16)r;
}

__device__ __forceinline__ u32 pk2bf(float a, float b) {
    float2 f2; f2.x = a; f2.y = b;
    __hip_bfloat162 h = __float22bfloat162_rn(f2);
    union { __hip_bfloat162 h; u32 u; } cv; cv.h = h;
    return cv.u;
}

__device__ __forceinline__ void async_copy16(u16* lds, const u16* g) {
    __builtin_amdgcn_global_load_lds((const __attribute__((address_space(1))) u32*)g,
                                     (__attribute__((address_space(3))) u32*)lds,
                                     16, 0, 0);
}

// ---------------- pack weights: transpose [2048 k][128 h] fp32 x3 -> bf16 Wp[384 h][2048 k]
__global__ void pack_weights(const float* __restrict__ Wq, const float* __restrict__ Wk,
                             const float* __restrict__ Wv, u16* __restrict__ Wp) {
    __shared__ u16 tl[64 * 64];
    int t = threadIdx.x;
    int bx = blockIdx.x;                 // 3 w * 32 kt * 2 ht = 192
    int w = bx >> 6;
    int kt = (bx >> 1) & 31;
    int ht = bx & 1;
    int k0 = kt * 64, h0 = ht * 64;
    const float* W = (w == 0) ? Wq : ((w == 1) ? Wk : Wv);

    int kl = t >> 2, hc = t & 3;
    const float* src = W + (size_t)(k0 + kl) * HDIM + h0 + hc * 16;
#pragma unroll
    for (int half = 0; half < 2; half++) {
        bf16x8 p;
#pragma unroll
        for (int j = 0; j < 8; j++) p[j] = (short)f2bf(src[half * 8 + j]);
        int slot = hc * 2 + half;
        *(bf16x8*)((char*)tl + kl * 128 + ((slot ^ (kl & 7)) << 4)) = p;
    }
    __syncthreads();
    int hl = t >> 2, kc = t & 3;
    u16* dst = Wp + (size_t)(w * HDIM + h0 + hl) * DMODEL + k0 + kc * 16;
#pragma unroll
    for (int half = 0; half < 2; half++) {
        bf16x8 p;
#pragma unroll
        for (int j = 0; j < 8; j++) {
            int k = kc * 16 + half * 8 + j;
            p[j] = *(u16*)((char*)tl + k * 128 + (((hl >> 3) ^ (k & 7)) << 4) + (hl & 7) * 2);
        }
        *(bf16x8*)(dst + half * 8) = p;
    }
}

// ---------------- fused QKV projection GEMM: [16384,2048] @ [2048,384] (bf16 MFMA)
// RING-3 COUNTED PIPELINE (r20). The r7/r10/r14 vmcnt(2) waited for B(p+1) ISSUED THE
// SAME PHASE -> ~1-3k cyc drain per phase (the reproducible 2.3us/phase). Now: Bs and
// As are 3-slot rings; phase p issues B(p+2)+A(p+2) (5 VMEM ops) then vmcnt(5) --
// leaves the current phase fully in flight; B(p) was issued 2 phases ago -> zero
// drain. Cross-wave safety: each wave's vmcnt(5) at phase p-1 drains its own <=p-2
// issues; the end-of-phase barrier then makes B(p) globally visible.
// BM=64, BN=192 (grid 512, A read 2x = 142MB, affordable), BK=64, 8 waves (2m x 4n),
// coalesced A staging (r13's failure was LANE-STRIDED A loads, not depth). LDS 96KB.
// Ledger: BK=32 bank-conflicts (r8); LDS-free (r9); same-phase vmcnt drain (r7/r10/
// r14); miscounted (r12); uncoalesced-A confound (r13).
__launch_bounds__(512)
__global__ void qkv_gemm(const float* __restrict__ hs, const u16* __restrict__ Wp,
                         const float* __restrict__ bq, const float* __restrict__ bk,
                         const float* __restrict__ bv,
                         u16* __restrict__ Qb, u16* __restrict__ Kb, u16* __restrict__ Vt) {
    __shared__ u16 As[3][64 * 64];       // 3 x 8 KB ring, 16B-slot XOR swizzle
    __shared__ u16 Bs[3][192 * 64];      // 3 x 24 KB ring, swizzled

    int t = threadIdx.x;
    int wv = t >> 6, l = t & 63, lr = l & 15, lq = l >> 4;
    int wm = wv >> 2, wn = wv & 3;
    int m0 = (blockIdx.x >> 1) * 64;
    int col0 = (blockIdx.x & 1) * 192;
    int ko = ((blockIdx.x >> 3) & 31) << 6;   // k-ring start (L2 hotspot de-phasing, r14)

#define KW(X) (((X) + ko) & (DMODEL - 1))

    f32x4 acc[2][3] = {};

    int ar = t >> 3, aq = t & 7;         // A staging: row 0..63, 8-float chunk (coalesced)
    const float* gA = hs + (size_t)(m0 + ar) * DMODEL + aq * 8;

    f32x4 a0[3], a1[3];                  // 3 A-prefetch register sets (ring)

#define STAGE_B(K0, BUF)                                                    \
    {                                                                       \
        _Pragma("unroll")                                                   \
        for (int i = 0; i < 3; i++) {                                       \
            int c = i * 512 + t;                                            \
            int n = c >> 3, s = c & 7;                                      \
            async_copy16(&Bs[BUF][c * 8],                                   \
                         Wp + (size_t)(col0 + n) * DMODEL + (K0) + ((s ^ (n & 7)) * 8)); \
        }                                                                   \
    }
#define LOAD_A(SET, K)                                                      \
    { a0[SET] = *(const f32x4*)(gA + (K)); a1[SET] = *(const f32x4*)(gA + (K) + 4); }
#define WRITE_A(BUF, SET)                                                   \
    {                                                                       \
        u32x4 pk;                                                           \
        pk.x = pk2bf(a0[SET][0], a0[SET][1]); pk.y = pk2bf(a0[SET][2], a0[SET][3]); \
        pk.z = pk2bf(a1[SET][0], a1[SET][1]); pk.w = pk2bf(a1[SET][2], a1[SET][3]); \
        *(u32x4*)((char*)&As[BUF][0] + ar * 128 + ((aq ^ (ar & 7)) << 4)) = pk; \
    }
#define COMPUTE(J)                                                          \
    {                                                                       \
        _Pragma("unroll")                                                   \
        for (int kk = 0; kk < 2; kk++) {                                    \
            bf16x8 afr[2], bfr[3];                                          \
            int slot = kk * 4 + lq;                                         \
            _Pragma("unroll")                                               \
            for (int mi = 0; mi < 2; mi++) {                                \
                int row = wm * 32 + mi * 16 + lr;                           \
                afr[mi] = *(bf16x8*)((char*)&As[J][0] + row * 128 + ((slot ^ (row & 7)) << 4)); \
            }                                                               \
            _Pragma("unroll")                                               \
            for (int ni = 0; ni < 3; ni++) {                                \
                int row = wn * 48 + ni * 16 + lr;                           \
                bfr[ni] = *(bf16x8*)((char*)&Bs[J][0] + row * 128 + ((slot ^ (row & 7)) << 4)); \
            }                                                               \
            __builtin_amdgcn_s_setprio(1);                                  \
            _Pragma("unroll")                                               \
            for (int mi = 0; mi < 2; mi++)                                  \
                _Pragma("unroll")                                           \
                for (int ni = 0; ni < 3; ni++)                              \
                    acc[mi][ni] = __builtin_amdgcn_mfma_f32_16x16x32_bf16(afr[mi], bfr[ni], acc[mi][ni], 0, 0, 0); \
            __builtin_amdgcn_s_setprio(0);                                  \
        }                                                                   \
    }
// Phase p (J=p%3, tile index T=K0/64+J): stage B(T+2)->slot (J+2)%3; load A(T+2)->set
// (J+2)%3; vmcnt(5) keeps THIS phase's 5 ops in flight (drains <= p-1: B(p+1),A(p+1));
// compute tile T from ring slot J; ds_write A(T+1) into slot (J+1)%3; lgkm0+barrier.
#define QPHASE(J, K0)                                                       \
    {                                                                       \
        int kN = KW((K0) + ((J) + 2) * 64);                                 \
        STAGE_B(kN, ((J) + 2) % 3);                                         \
        LOAD_A(((J) + 2) % 3, kN);                                          \
        __builtin_amdgcn_sched_barrier(0);                                  \
        asm volatile("s_waitcnt vmcnt(5)" ::: "memory");                    \
        __builtin_amdgcn_sched_barrier(0);                                  \
        COMPUTE(J);                                                         \
        WRITE_A(((J) + 1) % 3, ((J) + 1) % 3);                              \
        asm volatile("s_waitcnt lgkmcnt(0)" ::: "memory");                  \
        __builtin_amdgcn_sched_barrier(0);                                  \
        __builtin_amdgcn_s_barrier();                                       \
        __builtin_amdgcn_sched_barrier(0);                                  \
    }

    // prologue: tiles 0,1 in flight; per-wave vmcnt(5) -> own B(0),A(0) landed; write
    // A(0) into slot 0; barrier makes B(0)/As(0) globally visible for phase 0.
    STAGE_B(KW(0), 0);
    LOAD_A(0, KW(0));
    STAGE_B(KW(64), 1);
    LOAD_A(1, KW(64));
    __builtin_amdgcn_sched_barrier(0);
    asm volatile("s_waitcnt vmcnt(5)" ::: "memory");
    __builtin_amdgcn_sched_barrier(0);
    WRITE_A(0, 0);
    asm volatile("s_waitcnt lgkmcnt(0)" ::: "memory");
    __builtin_amdgcn_sched_barrier(0);
    __builtin_amdgcn_s_barrier();
    __builtin_amdgcn_sched_barrier(0);

    for (int it = 0; it < 10; ++it) {
        int kb = it * 192;
        QPHASE(0, kb)
        QPHASE(1, kb)
        QPHASE(2, kb)
    }
    QPHASE(0, 1920)   // tile 30 (slot 0); prefetch wraps via KW (junk, unused)
    QPHASE(1, 1920)   // tile 31 (slot 1)

    // epilogue: bias; Q pre-scaled by 1/sqrt(128); V written transposed to Vt[b][h][s]
#pragma unroll
    for (int ni = 0; ni < 3; ni++) {
        int col = col0 + wn * 48 + ni * 16 + lr;
        int w = col >> 7, h = col & 127;
        const float* bp = (w == 0) ? bq : ((w == 1) ? bk : bv);
        float bias = bp[h];
#pragma unroll
        for (int mi = 0; mi < 2; mi++) {
            int row0 = m0 + wm * 32 + mi * 16 + lq * 4;
            if (w == 2) {
                int b = row0 >> 11, s0 = row0 & (S_LEN - 1);
                bf16x4 pv;
#pragma unroll
                for (int r = 0; r < 4; r++) pv[r] = (short)f2bf(acc[mi][ni][r] + bias);
                *(bf16x4*)(Vt + (size_t)(b * HDIM + h) * S_LEN + s0) = pv;
            } else {
                float scale = (w == 0) ? 0.08838834764831845f : 1.0f;
                u16* dst = (w == 0) ? Qb : Kb;
#pragma unroll
                for (int r = 0; r < 4; r++)
                    dst[(size_t)(row0 + r) * HDIM + h] = f2bf((acc[mi][ni][r] + bias) * scale);
            }
        }
    }
#undef STAGE_B
#undef LOAD_A
#undef WRITE_A
#undef COMPUTE
#undef QPHASE
#undef KW
}

// ---------------- causal flash attention, QBLK=32 per wave (r19, VALIDATED: -15.6us).
// Wave owns 32 q-rows (2 MFMA row-groups); block = 4 waves KV-split over the SAME 32
// rows; grid 512 (8 b x 64 qt). Heaviest wave: 8 tiles (was 32 -> makespan fix).
// K/V fetched once per tile serves 2x rows. LDS 65KB -> 2 blocks/CU.
// launch_bounds(256,2). Defer-max (THR=8) + shuffle-free softmax (r15). FROZEN.
__launch_bounds__(256, 2)
__global__ void attn(const u16* __restrict__ Qb, const u16* __restrict__ Kb,
                     const u16* __restrict__ Vt, float* __restrict__ out) {
    __shared__ char lds[66560];          // Om[4][32][128] f32 (65536) + ml[4][32][2] f32 (1024)
    float* Om = (float*)lds;
    float* ml = (float*)(lds + 65536);

    int t = threadIdx.x;
    int wv = t >> 6, l = t & 63, lr = l & 15, lq = l >> 4;
    int bx = blockIdx.x;                 // 512 = 8 b x 64 qt
    int b = bx & 7;                      // batch == XCD for KV L2 locality
    int qt = 63 - (bx >> 3);             // descending work order: heavy blocks first
    int qr0 = qt * 32;
    size_t qbase = (size_t)b * S_LEN;
    char* Pw = lds + wv * 16384;         // P tile (32x128B = 4KB) aliases wave's Om region

    bf16x8 aqf[2][4];
#pragma unroll
    for (int mi = 0; mi < 2; mi++)
#pragma unroll
        for (int kk = 0; kk < 4; kk++)
            aqf[mi][kk] = *(const bf16x8*)(Qb + (qbase + qr0 + mi * 16 + lr) * HDIM + kk * 32 + lq * 8);

    f32x4 o_acc[2][8] = {};
    float m_run[2][4], l_run[2][4];
#pragma unroll
    for (int mi = 0; mi < 2; mi++)
#pragma unroll
        for (int r = 0; r < 4; r++) { m_run[mi][r] = -1e38f; l_run[mi][r] = 0.f; }

    int ktd = qt >> 1;                   // diagonal 64-wide tile index
    const u16* Kbase = Kb + qbase * HDIM;
    const u16* Vbase = Vt + (size_t)b * HDIM * S_LEN;

    int cnt = (ktd >= wv) ? (((ktd - wv) >> 2) + 1) : 0;

    for (int j = 0; j < cnt; ++j) {
        int kt = wv + (j << 2);
        int kv0 = kt * 64;

        // S = Q K^T for both 16-row groups; K loaded once per kk serves both
        f32x4 sa[2][4] = {};
#pragma unroll
        for (int kk = 0; kk < 4; kk++) {
            bf16x8 bk8[4];
#pragma unroll
            for (int n = 0; n < 4; n++)
                bk8[n] = *(const bf16x8*)(Kbase + (size_t)(kv0 + n * 16 + lr) * HDIM + kk * 32 + lq * 8);
            __builtin_amdgcn_s_setprio(1);
#pragma unroll
            for (int n = 0; n < 4; n++) {
                sa[0][n] = __builtin_amdgcn_mfma_f32_16x16x32_bf16(aqf[0][kk], bk8[n], sa[0][n], 0, 0, 0);
                sa[1][n] = __builtin_amdgcn_mfma_f32_16x16x32_bf16(aqf[1][kk], bk8[n], sa[1][n], 0, 0, 0);
            }
            __builtin_amdgcn_s_setprio(0);
        }

        if (kt == ktd) {                 // causal mask on the diagonal tile
#pragma unroll
            for (int n = 0; n < 4; n++) {
                int col = kv0 + n * 16 + lr;
#pragma unroll
                for (int mi = 0; mi < 2; mi++)
#pragma unroll
                    for (int r = 0; r < 4; r++) {
                        int row = qr0 + mi * 16 + lq * 4 + r;
                        if (col > row) sa[mi][n][r] = -1e30f;
                    }
            }
        }

        // shuffle-free online softmax (defer-max THR=8), both row groups
#pragma unroll
        for (int mi = 0; mi < 2; mi++) {
#pragma unroll
            for (int r = 0; r < 4; r++) {
                float pmx = fmaxf(fmaxf(sa[mi][0][r], sa[mi][1][r]), fmaxf(sa[mi][2][r], sa[mi][3][r]));
                if (__any(pmx > m_run[mi][r] + 8.0f)) {  // rare, wave-uniform
                    float mx = pmx;
#pragma unroll
                    for (int off = 8; off >= 1; off >>= 1) mx = fmaxf(mx, __shfl_xor(mx, off, 64));
                    float mnew = fmaxf(m_run[mi][r], mx);
                    float f = __expf(m_run[mi][r] - mnew);
                    l_run[mi][r] *= f;
                    m_run[mi][r] = mnew;
#pragma unroll
                    for (int n = 0; n < 8; n++) o_acc[mi][n][r] *= f;
                }
                int prow = mi * 16 + lq * 4 + r;
                char* pb = Pw + prow * 128;
#pragma unroll
                for (int n = 0; n < 4; n++) {
                    float e = __expf(sa[mi][n][r] - m_run[mi][r]);
                    l_run[mi][r] += e;               // per-lane partial, no shuffles
                    int col = n * 16 + lr;
                    *(u16*)(pb + (((col >> 3) ^ (prow & 7)) << 4) + (col & 7) * 2) = f2bf(e);
                }
            }
        }

        // O += P V : V loaded once per n serves both row groups
#pragma unroll
        for (int kk = 0; kk < 2; kk++) {
            int slot = kk * 4 + lq;
            int row0 = lr, row1 = 16 + lr;
            bf16x8 pa0 = *(bf16x8*)(Pw + row0 * 128 + ((slot ^ (row0 & 7)) << 4));
            bf16x8 pa1 = *(bf16x8*)(Pw + row1 * 128 + ((slot ^ (row1 & 7)) << 4));
            __builtin_amdgcn_s_setprio(1);
#pragma unroll
            for (int n = 0; n < 8; n++) {
                bf16x8 vb8 = *(const bf16x8*)(Vbase + (size_t)(n * 16 + lr) * S_LEN + kv0 + kk * 32 + lq * 8);
                o_acc[0][n] = __builtin_amdgcn_mfma_f32_16x16x32_bf16(pa0, vb8, o_acc[0][n], 0, 0, 0);
                o_acc[1][n] = __builtin_amdgcn_mfma_f32_16x16x32_bf16(pa1, vb8, o_acc[1][n], 0, 0, 0);
            }
            __builtin_amdgcn_s_setprio(0);
        }
    }

    // fold the per-lane l partials into group sums (once, not per tile)
#pragma unroll
    for (int mi = 0; mi < 2; mi++)
#pragma unroll
        for (int r = 0; r < 4; r++) {
#pragma unroll
            for (int off = 8; off >= 1; off >>= 1)
                l_run[mi][r] += __shfl_xor(l_run[mi][r], off, 64);
        }

    // write partials (Om[wv] overwrites this wave's P area only after its last P read)
    __builtin_amdgcn_sched_barrier(0);
#pragma unroll
    for (int mi = 0; mi < 2; mi++)
#pragma unroll
        for (int n = 0; n < 8; n++)
#pragma unroll
            for (int r = 0; r < 4; r++)
                Om[wv * 4096 + (mi * 16 + lq * 4 + r) * 128 + n * 16 + lr] = o_acc[mi][n][r];
    if (lr == 0) {
#pragma unroll
        for (int mi = 0; mi < 2; mi++)
#pragma unroll
            for (int r = 0; r < 4; r++) {
                int row = mi * 16 + lq * 4 + r;
                ml[wv * 64 + row * 2 + 0] = m_run[mi][r];
                ml[wv * 64 + row * 2 + 1] = l_run[mi][r];
            }
    }
    __syncthreads();

    // merge the 4 partials: thread -> (row = t>>3 in 0..31, cols (t&7)*16 .. +16)
    {
        int row = t >> 3, c0 = (t & 7) * 16;
        float m4[4], l4[4];
#pragma unroll
        for (int w = 0; w < 4; w++) {
            m4[w] = ml[w * 64 + row * 2 + 0];
            l4[w] = ml[w * 64 + row * 2 + 1];
        }
        float ms = fmaxf(fmaxf(m4[0], m4[1]), fmaxf(m4[2], m4[3]));
        float wt[4], ls = 0.f;
#pragma unroll
        for (int w = 0; w < 4; w++) { wt[w] = __expf(m4[w] - ms); ls += l4[w] * wt[w]; }
        float inv = 1.0f / ls;
        f32x4 r0 = (f32x4)0.f, r1 = (f32x4)0.f, r2 = (f32x4)0.f, r3 = (f32x4)0.f;
#pragma unroll
        for (int w = 0; w < 4; w++) {
            const f32x4* Op = (const f32x4*)(Om + w * 4096 + row * 128 + c0);
            r0 += Op[0] * wt[w];
            r1 += Op[1] * wt[w];
            r2 += Op[2] * wt[w];
            r3 += Op[3] * wt[w];
        }
        f32x4* dst = (f32x4*)(out + (qbase + qr0 + row) * HDIM + c0);
        dst[0] = r0 * inv;
        dst[1] = r1 * inv;
        dst[2] = r2 * inv;
        dst[3] = r3 * inv;
    }
}

extern "C" void kernel_launch(void* const* d_in, const int* in_sizes, int n_in,
                              void* d_out, int out_size, void* d_ws, size_t ws_size,
                              hipStream_t stream) {
    const float* hs = (const float*)d_in[0];
    const float* Wq = (const float*)d_in[1];
    const float* bq = (const float*)d_in[2];
    const float* Wk = (const float*)d_in[3];
    const float* bk = (const float*)d_in[4];
    const float* Wv = (const float*)d_in[5];
    const float* bv = (const float*)d_in[6];
    float* out = (float*)d_out;

    char* ws = (char*)d_ws;
    u16* Qb = (u16*)(ws);                       // 4 MB  [16384][128] bf16 (pre-scaled)
    u16* Kb = (u16*)(ws + (size_t)(4  << 20));  // 4 MB
    u16* Vt = (u16*)(ws + (size_t)(8  << 20));  // 4 MB  [8][128][2048] (written by qkv epilogue)
    u16* Wp = (u16*)(ws + (size_t)(12 << 20));  // 1.5 MB [384][2048]

    hipLaunchKernelGGL(pack_weights, dim3(192), dim3(256), 0, stream, Wq, Wk, Wv, Wp);
    hipLaunchKernelGGL(qkv_gemm, dim3(512), dim3(512), 0, stream, hs, Wp, bq, bk, bv, Qb, Kb, Vt);
    hipLaunchKernelGGL(attn, dim3(512), dim3(256), 0, stream, Qb, Kb, Vt, out);
}

// Round 21
// 100.713 us; speedup vs baseline: 1.2586x; 1.2586x over previous
//
#include <hip/hip_runtime.h>
#include <hip/hip_bf16.h>
#include <stdint.h>

#define B_DIM 8
#define S_LEN 2048
#define DMODEL 2048
#define HDIM 128

typedef __attribute__((ext_vector_type(4))) float f32x4;
typedef __attribute__((ext_vector_type(8))) short bf16x8;
typedef __attribute__((ext_vector_type(4))) short bf16x4;
typedef __attribute__((ext_vector_type(4))) unsigned int u32x4;
typedef unsigned short u16;
typedef unsigned int u32;

__device__ __forceinline__ u16 f2bf(float f) {
    union { float f; u32 u; } v; v.f = f;
    u32 u = v.u;
    u32 r = (u + 0x7fffu + ((u >> 16) & 1u)) >> 16;
    return (u16)r;
}

__device__ __forceinline__ u32 pk2bf(float a, float b) {
    float2 f2; f2.x = a; f2.y = b;
    __hip_bfloat162 h = __float22bfloat162_rn(f2);
    union { __hip_bfloat162 h; u32 u; } cv; cv.h = h;
    return cv.u;
}

__device__ __forceinline__ void async_copy16(u16* lds, const u16* g) {
    __builtin_amdgcn_global_load_lds((const __attribute__((address_space(1))) u32*)g,
                                     (__attribute__((address_space(3))) u32*)lds,
                                     16, 0, 0);
}

// ---------------- pack weights: transpose [2048 k][128 h] fp32 x3 -> bf16 Wp[384 h][2048 k]
__global__ void pack_weights(const float* __restrict__ Wq, const float* __restrict__ Wk,
                             const float* __restrict__ Wv, u16* __restrict__ Wp) {
    __shared__ u16 tl[64 * 64];
    int t = threadIdx.x;
    int bx = blockIdx.x;                 // 3 w * 32 kt * 2 ht = 192
    int w = bx >> 6;
    int kt = (bx >> 1) & 31;
    int ht = bx & 1;
    int k0 = kt * 64, h0 = ht * 64;
    const float* W = (w == 0) ? Wq : ((w == 1) ? Wk : Wv);

    int kl = t >> 2, hc = t & 3;
    const float* src = W + (size_t)(k0 + kl) * HDIM + h0 + hc * 16;
#pragma unroll
    for (int half = 0; half < 2; half++) {
        bf16x8 p;
#pragma unroll
        for (int j = 0; j < 8; j++) p[j] = (short)f2bf(src[half * 8 + j]);
        int slot = hc * 2 + half;
        *(bf16x8*)((char*)tl + kl * 128 + ((slot ^ (kl & 7)) << 4)) = p;
    }
    __syncthreads();
    int hl = t >> 2, kc = t & 3;
    u16* dst = Wp + (size_t)(w * HDIM + h0 + hl) * DMODEL + k0 + kc * 16;
#pragma unroll
    for (int half = 0; half < 2; half++) {
        bf16x8 p;
#pragma unroll
        for (int j = 0; j < 8; j++) {
            int k = kc * 16 + half * 8 + j;
            p[j] = *(u16*)((char*)tl + k * 128 + (((hl >> 3) ^ (k & 7)) << 4) + (hl & 7) * 2);
        }
        *(bf16x8*)(dst + half * 8) = p;
    }
}

// ---------------- fused QKV projection GEMM: [16384,2048] @ [2048,384] (bf16 MFMA)
// r14 kernel, REVERTED after r20: BM=64, BN=384, BK=64, grid 256, 8 waves, vmcnt(2),
// per-block k-ring offset. FROZEN PERMANENTLY. Ledger of dead ends: BK=32 bank
// conflicts (r8); LDS-free (r9); BN=192/2blk (r10); ring-3/4 counted depth with
// correct vmcnt (r12/r13/r20 — all >= 74us; ~2.3us/phase floor is NOT wave-schedule
// controlled). 74us dispatch is this structure's floor.
__launch_bounds__(512)
__global__ void qkv_gemm(const float* __restrict__ hs, const u16* __restrict__ Wp,
                         const float* __restrict__ bq, const float* __restrict__ bk,
                         const float* __restrict__ bv,
                         u16* __restrict__ Qb, u16* __restrict__ Kb, u16* __restrict__ Vt) {
    __shared__ u16 As[2][64 * 64];       // 2 x 8 KB, 16B-slot XOR swizzle
    __shared__ u16 Bs[2][384 * 64];      // 2 x 48 KB, swizzled

    int t = threadIdx.x;
    int wv = t >> 6, l = t & 63, lr = l & 15, lq = l >> 4;
    int wm = wv >> 2, wn = wv & 3;
    int m0 = blockIdx.x * 64;
    int ko = ((blockIdx.x >> 3) & 31) << 6;   // k-ring start: unique per block within an XCD

#define KW(X) (((X) + ko) & (DMODEL - 1))

    f32x4 acc[2][6] = {};

    int ar = t >> 3, aq = t & 7;         // A staging: row 0..63, 8-float chunk 0..7
    const float* gA = hs + (size_t)(m0 + ar) * DMODEL + aq * 8;

    f32x4 p0A, p1A, p0B, p1B;            // two A-prefetch register sets (depth 2)

#define STAGE_B(K0, BUF)                                                    \
    {                                                                       \
        _Pragma("unroll")                                                   \
        for (int i = 0; i < 6; i++) {                                       \
            int c = i * 512 + t;                                            \
            int n = c >> 3, s = c & 7;                                      \
            async_copy16(&Bs[BUF][c * 8],                                   \
                         Wp + (size_t)n * DMODEL + (K0) + ((s ^ (n & 7)) * 8)); \
        }                                                                   \
    }
#define WRITE_A(BUF, V0, V1)                                                \
    {                                                                       \
        u32x4 pk;                                                           \
        pk.x = pk2bf(V0[0], V0[1]); pk.y = pk2bf(V0[2], V0[3]);             \
        pk.z = pk2bf(V1[0], V1[1]); pk.w = pk2bf(V1[2], V1[3]);             \
        *(u32x4*)((char*)&As[BUF][0] + ar * 128 + ((aq ^ (ar & 7)) << 4)) = pk; \
    }
#define COMPUTE(CUR)                                                        \
    {                                                                       \
        _Pragma("unroll")                                                   \
        for (int kk = 0; kk < 2; kk++) {                                    \
            bf16x8 afr[2], bfr[6];                                          \
            int slot = kk * 4 + lq;                                         \
            _Pragma("unroll")                                               \
            for (int mi = 0; mi < 2; mi++) {                                \
                int row = wm * 32 + mi * 16 + lr;                           \
                afr[mi] = *(bf16x8*)((char*)&As[CUR][0] + row * 128 + ((slot ^ (row & 7)) << 4)); \
            }                                                               \
            _Pragma("unroll")                                               \
            for (int ni = 0; ni < 6; ni++) {                                \
                int row = wn * 96 + ni * 16 + lr;                           \
                bfr[ni] = *(bf16x8*)((char*)&Bs[CUR][0] + row * 128 + ((slot ^ (row & 7)) << 4)); \
            }                                                               \
            __builtin_amdgcn_s_setprio(1);                                  \
            _Pragma("unroll")                                               \
            for (int mi = 0; mi < 2; mi++)                                  \
                _Pragma("unroll")                                           \
                for (int ni = 0; ni < 6; ni++)                              \
                    acc[mi][ni] = __builtin_amdgcn_mfma_f32_16x16x32_bf16(afr[mi], bfr[ni], acc[mi][ni], 0, 0, 0); \
            __builtin_amdgcn_s_setprio(0);                                  \
        }                                                                   \
    }
#define SYNC_PIPE                                                           \
    asm volatile("s_waitcnt vmcnt(2) lgkmcnt(0)" ::: "memory");             \
    __builtin_amdgcn_sched_barrier(0);                                      \
    __builtin_amdgcn_s_barrier();                                           \
    __builtin_amdgcn_sched_barrier(0);

    // prologue: tile ko into buf0; prefetch A(ko+64)
    p0A = *(const f32x4*)(gA + KW(0)); p1A = *(const f32x4*)(gA + KW(0) + 4);
    STAGE_B(KW(0), 0);
    WRITE_A(0, p0A, p1A);
    p0A = *(const f32x4*)(gA + KW(64)); p1A = *(const f32x4*)(gA + KW(64) + 4);
    __syncthreads();                     // full drain once (prologue only)

    for (int k0 = 0; k0 < DMODEL; k0 += 128) {
        // even step: compute buf0; stage tile(i+1)->buf1; prefetch A(i+2)
        {
            int ks = KW(k0 + 64);
            int kp = KW(k0 + 128);
            STAGE_B(ks, 1);
            p0B = *(const f32x4*)(gA + kp); p1B = *(const f32x4*)(gA + kp + 4);
            COMPUTE(0);
            WRITE_A(1, p0A, p1A);
            SYNC_PIPE
        }
        // odd step: compute buf1; stage->buf0; prefetch
        {
            int ks = KW(k0 + 128);
            int kp = KW(k0 + 192);
            STAGE_B(ks, 0);
            p0A = *(const f32x4*)(gA + kp); p1A = *(const f32x4*)(gA + kp + 4);
            COMPUTE(1);
            WRITE_A(0, p0B, p1B);
            SYNC_PIPE
        }
    }

    // epilogue: bias; Q pre-scaled by 1/sqrt(128); V written transposed to Vt[b][h][s]
#pragma unroll
    for (int ni = 0; ni < 6; ni++) {
        int col = wn * 96 + ni * 16 + lr;
        int w = col >> 7, h = col & 127;
        const float* bp = (w == 0) ? bq : ((w == 1) ? bk : bv);
        float bias = bp[h];
#pragma unroll
        for (int mi = 0; mi < 2; mi++) {
            int row0 = m0 + wm * 32 + mi * 16 + lq * 4;
            if (w == 2) {
                int b = row0 >> 11, s0 = row0 & (S_LEN - 1);
                bf16x4 pv;
#pragma unroll
                for (int r = 0; r < 4; r++) pv[r] = (short)f2bf(acc[mi][ni][r] + bias);
                *(bf16x4*)(Vt + (size_t)(b * HDIM + h) * S_LEN + s0) = pv;
            } else {
                float scale = (w == 0) ? 0.08838834764831845f : 1.0f;
                u16* dst = (w == 0) ? Qb : Kb;
#pragma unroll
                for (int r = 0; r < 4; r++)
                    dst[(size_t)(row0 + r) * HDIM + h] = f2bf((acc[mi][ni][r] + bias) * scale);
            }
        }
    }
#undef STAGE_B
#undef WRITE_A
#undef COMPUTE
#undef SYNC_PIPE
#undef KW
}

// ---------------- causal flash attention, QBLK=32 per wave (r19, VALIDATED: -15.6us).
// Wave owns 32 q-rows (2 MFMA row-groups); block = 4 waves KV-split over the SAME 32
// rows; grid 512 (8 b x 64 qt). Heaviest wave: 8 tiles. LDS 65KB -> 2 blocks/CU.
// COMPLEMENT PAIRING (r21): grid = exactly 2 blocks/CU; blocks bx and bx+256 (same
// bx&7 -> same XCD slot) co-reside. Old qt = 63-(bx>>3) paired (63,31)...(32,0):
// 3x per-CU work imbalance -> makespan. Remap i=bx>>3: qt = i<32 ? 63-i : i-32 pairs
// qt with complement (sum 63 for every pair) -> equal work per CU. Pure permutation.
// launch_bounds(256,2). Defer-max (THR=8) + shuffle-free softmax (r15).
__launch_bounds__(256, 2)
__global__ void attn(const u16* __restrict__ Qb, const u16* __restrict__ Kb,
                     const u16* __restrict__ Vt, float* __restrict__ out) {
    __shared__ char lds[66560];          // Om[4][32][128] f32 (65536) + ml[4][32][2] f32 (1024)
    float* Om = (float*)lds;
    float* ml = (float*)(lds + 65536);

    int t = threadIdx.x;
    int wv = t >> 6, l = t & 63, lr = l & 15, lq = l >> 4;
    int bx = blockIdx.x;                 // 512 = 8 b x 64 qt
    int b = bx & 7;                      // batch == XCD for KV L2 locality
    int i = bx >> 3;
    int qt = (i < 32) ? (63 - i) : (i - 32);   // complement pairing
    int qr0 = qt * 32;
    size_t qbase = (size_t)b * S_LEN;
    char* Pw = lds + wv * 16384;         // P tile (32x128B = 4KB) aliases wave's Om region

    bf16x8 aqf[2][4];
#pragma unroll
    for (int mi = 0; mi < 2; mi++)
#pragma unroll
        for (int kk = 0; kk < 4; kk++)
            aqf[mi][kk] = *(const bf16x8*)(Qb + (qbase + qr0 + mi * 16 + lr) * HDIM + kk * 32 + lq * 8);

    f32x4 o_acc[2][8] = {};
    float m_run[2][4], l_run[2][4];
#pragma unroll
    for (int mi = 0; mi < 2; mi++)
#pragma unroll
        for (int r = 0; r < 4; r++) { m_run[mi][r] = -1e38f; l_run[mi][r] = 0.f; }

    int ktd = qt >> 1;                   // diagonal 64-wide tile index
    const u16* Kbase = Kb + qbase * HDIM;
    const u16* Vbase = Vt + (size_t)b * HDIM * S_LEN;

    int cnt = (ktd >= wv) ? (((ktd - wv) >> 2) + 1) : 0;

    for (int j = 0; j < cnt; ++j) {
        int kt = wv + (j << 2);
        int kv0 = kt * 64;

        // S = Q K^T for both 16-row groups; K loaded once per kk serves both
        f32x4 sa[2][4] = {};
#pragma unroll
        for (int kk = 0; kk < 4; kk++) {
            bf16x8 bk8[4];
#pragma unroll
            for (int n = 0; n < 4; n++)
                bk8[n] = *(const bf16x8*)(Kbase + (size_t)(kv0 + n * 16 + lr) * HDIM + kk * 32 + lq * 8);
            __builtin_amdgcn_s_setprio(1);
#pragma unroll
            for (int n = 0; n < 4; n++) {
                sa[0][n] = __builtin_amdgcn_mfma_f32_16x16x32_bf16(aqf[0][kk], bk8[n], sa[0][n], 0, 0, 0);
                sa[1][n] = __builtin_amdgcn_mfma_f32_16x16x32_bf16(aqf[1][kk], bk8[n], sa[1][n], 0, 0, 0);
            }
            __builtin_amdgcn_s_setprio(0);
        }

        if (kt == ktd) {                 // causal mask on the diagonal tile
#pragma unroll
            for (int n = 0; n < 4; n++) {
                int col = kv0 + n * 16 + lr;
#pragma unroll
                for (int mi = 0; mi < 2; mi++)
#pragma unroll
                    for (int r = 0; r < 4; r++) {
                        int row = qr0 + mi * 16 + lq * 4 + r;
                        if (col > row) sa[mi][n][r] = -1e30f;
                    }
            }
        }

        // shuffle-free online softmax (defer-max THR=8), both row groups
#pragma unroll
        for (int mi = 0; mi < 2; mi++) {
#pragma unroll
            for (int r = 0; r < 4; r++) {
                float pmx = fmaxf(fmaxf(sa[mi][0][r], sa[mi][1][r]), fmaxf(sa[mi][2][r], sa[mi][3][r]));
                if (__any(pmx > m_run[mi][r] + 8.0f)) {  // rare, wave-uniform
                    float mx = pmx;
#pragma unroll
                    for (int off = 8; off >= 1; off >>= 1) mx = fmaxf(mx, __shfl_xor(mx, off, 64));
                    float mnew = fmaxf(m_run[mi][r], mx);
                    float f = __expf(m_run[mi][r] - mnew);
                    l_run[mi][r] *= f;
                    m_run[mi][r] = mnew;
#pragma unroll
                    for (int n = 0; n < 8; n++) o_acc[mi][n][r] *= f;
                }
                int prow = mi * 16 + lq * 4 + r;
                char* pb = Pw + prow * 128;
#pragma unroll
                for (int n = 0; n < 4; n++) {
                    float e = __expf(sa[mi][n][r] - m_run[mi][r]);
                    l_run[mi][r] += e;               // per-lane partial, no shuffles
                    int col = n * 16 + lr;
                    *(u16*)(pb + (((col >> 3) ^ (prow & 7)) << 4) + (col & 7) * 2) = f2bf(e);
                }
            }
        }

        // O += P V : V loaded once per n serves both row groups
#pragma unroll
        for (int kk = 0; kk < 2; kk++) {
            int slot = kk * 4 + lq;
            int row0 = lr, row1 = 16 + lr;
            bf16x8 pa0 = *(bf16x8*)(Pw + row0 * 128 + ((slot ^ (row0 & 7)) << 4));
            bf16x8 pa1 = *(bf16x8*)(Pw + row1 * 128 + ((slot ^ (row1 & 7)) << 4));
            __builtin_amdgcn_s_setprio(1);
#pragma unroll
            for (int n = 0; n < 8; n++) {
                bf16x8 vb8 = *(const bf16x8*)(Vbase + (size_t)(n * 16 + lr) * S_LEN + kv0 + kk * 32 + lq * 8);
                o_acc[0][n] = __builtin_amdgcn_mfma_f32_16x16x32_bf16(pa0, vb8, o_acc[0][n], 0, 0, 0);
                o_acc[1][n] = __builtin_amdgcn_mfma_f32_16x16x32_bf16(pa1, vb8, o_acc[1][n], 0, 0, 0);
            }
            __builtin_amdgcn_s_setprio(0);
        }
    }

    // fold the per-lane l partials into group sums (once, not per tile)
#pragma unroll
    for (int mi = 0; mi < 2; mi++)
#pragma unroll
        for (int r = 0; r < 4; r++) {
#pragma unroll
            for (int off = 8; off >= 1; off >>= 1)
                l_run[mi][r] += __shfl_xor(l_run[mi][r], off, 64);
        }

    // write partials (Om[wv] overwrites this wave's P area only after its last P read)
    __builtin_amdgcn_sched_barrier(0);
#pragma unroll
    for (int mi = 0; mi < 2; mi++)
#pragma unroll
        for (int n = 0; n < 8; n++)
#pragma unroll
            for (int r = 0; r < 4; r++)
                Om[wv * 4096 + (mi * 16 + lq * 4 + r) * 128 + n * 16 + lr] = o_acc[mi][n][r];
    if (lr == 0) {
#pragma unroll
        for (int mi = 0; mi < 2; mi++)
#pragma unroll
            for (int r = 0; r < 4; r++) {
                int row = mi * 16 + lq * 4 + r;
                ml[wv * 64 + row * 2 + 0] = m_run[mi][r];
                ml[wv * 64 + row * 2 + 1] = l_run[mi][r];
            }
    }
    __syncthreads();

    // merge the 4 partials: thread -> (row = t>>3 in 0..31, cols (t&7)*16 .. +16)
    {
        int row = t >> 3, c0 = (t & 7) * 16;
        float m4[4], l4[4];
#pragma unroll
        for (int w = 0; w < 4; w++) {
            m4[w] = ml[w * 64 + row * 2 + 0];
            l4[w] = ml[w * 64 + row * 2 + 1];
        }
        float ms = fmaxf(fmaxf(m4[0], m4[1]), fmaxf(m4[2], m4[3]));
        float wt[4], ls = 0.f;
#pragma unroll
        for (int w = 0; w < 4; w++) { wt[w] = __expf(m4[w] - ms); ls += l4[w] * wt[w]; }
        float inv = 1.0f / ls;
        f32x4 r0 = (f32x4)0.f, r1 = (f32x4)0.f, r2 = (f32x4)0.f, r3 = (f32x4)0.f;
#pragma unroll
        for (int w = 0; w < 4; w++) {
            const f32x4* Op = (const f32x4*)(Om + w * 4096 + row * 128 + c0);
            r0 += Op[0] * wt[w];
            r1 += Op[1] * wt[w];
            r2 += Op[2] * wt[w];
            r3 += Op[3] * wt[w];
        }
        f32x4* dst = (f32x4*)(out + (qbase + qr0 + row) * HDIM + c0);
        dst[0] = r0 * inv;
        dst[1] = r1 * inv;
        dst[2] = r2 * inv;
        dst[3] = r3 * inv;
    }
}

extern "C" void kernel_launch(void* const* d_in, const int* in_sizes, int n_in,
                              void* d_out, int out_size, void* d_ws, size_t ws_size,
                              hipStream_t stream) {
    const float* hs = (const float*)d_in[0];
    const float* Wq = (const float*)d_in[1];
    const float* bq = (const float*)d_in[2];
    const float* Wk = (const float*)d_in[3];
    const float* bk = (const float*)d_in[4];
    const float* Wv = (const float*)d_in[5];
    const float* bv = (const float*)d_in[6];
    float* out = (float*)d_out;

    char* ws = (char*)d_ws;
    u16* Qb = (u16*)(ws);                       // 4 MB  [16384][128] bf16 (pre-scaled)
    u16* Kb = (u16*)(ws + (size_t)(4  << 20));  // 4 MB
    u16* Vt = (u16*)(ws + (size_t)(8  << 20));  // 4 MB  [8][128][2048] (written by qkv epilogue)
    u16* Wp = (u16*)(ws + (size_t)(12 << 20));  // 1.5 MB [384][2048]

    hipLaunchKernelGGL(pack_weights, dim3(192), dim3(256), 0, stream, Wq, Wk, Wv, Wp);
    hipLaunchKernelGGL(qkv_gemm, dim3(256), dim3(512), 0, stream, hs, Wp, bq, bk, bv, Qb, Kb, Vt);
    hipLaunchKernelGGL(attn, dim3(512), dim3(256), 0, stream, Qb, Kb, Vt, out);
}

// Round 22
// 92.103 us; speedup vs baseline: 1.3763x; 1.0935x over previous
//
#include <hip/hip_runtime.h>
#include <hip/hip_bf16.h>
#include <stdint.h>

#define B_DIM 8
#define S_LEN 2048
#define DMODEL 2048
#define HDIM 128

typedef __attribute__((ext_vector_type(4))) float f32x4;
typedef __attribute__((ext_vector_type(8))) short bf16x8;
typedef __attribute__((ext_vector_type(4))) short bf16x4;
typedef __attribute__((ext_vector_type(4))) unsigned int u32x4;
typedef unsigned short u16;
typedef unsigned int u32;

__device__ __forceinline__ u16 f2bf(float f) {
    union { float f; u32 u; } v; v.f = f;
    u32 u = v.u;
    u32 r = (u + 0x7fffu + ((u >> 16) & 1u)) >> 16;
    return (u16)r;
}

__device__ __forceinline__ u32 pk2bf(float a, float b) {
    float2 f2; f2.x = a; f2.y = b;
    __hip_bfloat162 h = __float22bfloat162_rn(f2);
    union { __hip_bfloat162 h; u32 u; } cv; cv.h = h;
    return cv.u;
}

__device__ __forceinline__ void async_copy16(u16* lds, const u16* g) {
    __builtin_amdgcn_global_load_lds((const __attribute__((address_space(1))) u32*)g,
                                     (__attribute__((address_space(3))) u32*)lds,
                                     16, 0, 0);
}

// ---------------- pack weights: transpose [2048 k][128 h] fp32 x3 -> bf16 Wp[384 h][2048 k]
__global__ void pack_weights(const float* __restrict__ Wq, const float* __restrict__ Wk,
                             const float* __restrict__ Wv, u16* __restrict__ Wp) {
    __shared__ u16 tl[64 * 64];
    int t = threadIdx.x;
    int bx = blockIdx.x;                 // 3 w * 32 kt * 2 ht = 192
    int w = bx >> 6;
    int kt = (bx >> 1) & 31;
    int ht = bx & 1;
    int k0 = kt * 64, h0 = ht * 64;
    const float* W = (w == 0) ? Wq : ((w == 1) ? Wk : Wv);

    int kl = t >> 2, hc = t & 3;
    const float* src = W + (size_t)(k0 + kl) * HDIM + h0 + hc * 16;
#pragma unroll
    for (int half = 0; half < 2; half++) {
        bf16x8 p;
#pragma unroll
        for (int j = 0; j < 8; j++) p[j] = (short)f2bf(src[half * 8 + j]);
        int slot = hc * 2 + half;
        *(bf16x8*)((char*)tl + kl * 128 + ((slot ^ (kl & 7)) << 4)) = p;
    }
    __syncthreads();
    int hl = t >> 2, kc = t & 3;
    u16* dst = Wp + (size_t)(w * HDIM + h0 + hl) * DMODEL + k0 + kc * 16;
#pragma unroll
    for (int half = 0; half < 2; half++) {
        bf16x8 p;
#pragma unroll
        for (int j = 0; j < 8; j++) {
            int k = kc * 16 + half * 8 + j;
            p[j] = *(u16*)((char*)tl + k * 128 + (((hl >> 3) ^ (k & 7)) << 4) + (hl & 7) * 2);
        }
        *(bf16x8*)(dst + half * 8) = p;
    }
}

// ---------------- fused QKV projection GEMM: [16384,2048] @ [2048,384] (bf16 MFMA)
// r14 structure, DE-PINNED (r22): removed s_setprio (m190: measured NEGATIVE on
// lockstep GEMM) and all sched_barrier(0) pins (m141: order-pinning defeats the
// compiler scheduler). Correctness: the "memory"-clobbered s_waitcnt asm orders all
// memory ops (gload_lds, ds_write, ds_read); MFMA operands arrive via ds_read ->
// ordered. BM=64, BN=384, BK=64, grid 256, 8 waves, vmcnt(2), k-ring offset.
// Ledger of dead ends: BK=32 (r8); LDS-free (r9); BN=192/2blk (r10); counted ring
// depth (r12/r13/r20).
__launch_bounds__(512)
__global__ void qkv_gemm(const float* __restrict__ hs, const u16* __restrict__ Wp,
                         const float* __restrict__ bq, const float* __restrict__ bk,
                         const float* __restrict__ bv,
                         u16* __restrict__ Qb, u16* __restrict__ Kb, u16* __restrict__ Vt) {
    __shared__ u16 As[2][64 * 64];       // 2 x 8 KB, 16B-slot XOR swizzle
    __shared__ u16 Bs[2][384 * 64];      // 2 x 48 KB, swizzled

    int t = threadIdx.x;
    int wv = t >> 6, l = t & 63, lr = l & 15, lq = l >> 4;
    int wm = wv >> 2, wn = wv & 3;
    int m0 = blockIdx.x * 64;
    int ko = ((blockIdx.x >> 3) & 31) << 6;   // k-ring start: unique per block within an XCD

#define KW(X) (((X) + ko) & (DMODEL - 1))

    f32x4 acc[2][6] = {};

    int ar = t >> 3, aq = t & 7;         // A staging: row 0..63, 8-float chunk 0..7
    const float* gA = hs + (size_t)(m0 + ar) * DMODEL + aq * 8;

    f32x4 p0A, p1A, p0B, p1B;            // two A-prefetch register sets (depth 2)

#define STAGE_B(K0, BUF)                                                    \
    {                                                                       \
        _Pragma("unroll")                                                   \
        for (int i = 0; i < 6; i++) {                                       \
            int c = i * 512 + t;                                            \
            int n = c >> 3, s = c & 7;                                      \
            async_copy16(&Bs[BUF][c * 8],                                   \
                         Wp + (size_t)n * DMODEL + (K0) + ((s ^ (n & 7)) * 8)); \
        }                                                                   \
    }
#define WRITE_A(BUF, V0, V1)                                                \
    {                                                                       \
        u32x4 pk;                                                           \
        pk.x = pk2bf(V0[0], V0[1]); pk.y = pk2bf(V0[2], V0[3]);             \
        pk.z = pk2bf(V1[0], V1[1]); pk.w = pk2bf(V1[2], V1[3]);             \
        *(u32x4*)((char*)&As[BUF][0] + ar * 128 + ((aq ^ (ar & 7)) << 4)) = pk; \
    }
#define COMPUTE(CUR)                                                        \
    {                                                                       \
        _Pragma("unroll")                                                   \
        for (int kk = 0; kk < 2; kk++) {                                    \
            bf16x8 afr[2], bfr[6];                                          \
            int slot = kk * 4 + lq;                                         \
            _Pragma("unroll")                                               \
            for (int mi = 0; mi < 2; mi++) {                                \
                int row = wm * 32 + mi * 16 + lr;                           \
                afr[mi] = *(bf16x8*)((char*)&As[CUR][0] + row * 128 + ((slot ^ (row & 7)) << 4)); \
            }                                                               \
            _Pragma("unroll")                                               \
            for (int ni = 0; ni < 6; ni++) {                                \
                int row = wn * 96 + ni * 16 + lr;                           \
                bfr[ni] = *(bf16x8*)((char*)&Bs[CUR][0] + row * 128 + ((slot ^ (row & 7)) << 4)); \
            }                                                               \
            _Pragma("unroll")                                               \
            for (int mi = 0; mi < 2; mi++)                                  \
                _Pragma("unroll")                                           \
                for (int ni = 0; ni < 6; ni++)                              \
                    acc[mi][ni] = __builtin_amdgcn_mfma_f32_16x16x32_bf16(afr[mi], bfr[ni], acc[mi][ni], 0, 0, 0); \
        }                                                                   \
    }
#define SYNC_PIPE                                                           \
    asm volatile("s_waitcnt vmcnt(2) lgkmcnt(0)" ::: "memory");             \
    __builtin_amdgcn_s_barrier();

    // prologue: tile ko into buf0; prefetch A(ko+64)
    p0A = *(const f32x4*)(gA + KW(0)); p1A = *(const f32x4*)(gA + KW(0) + 4);
    STAGE_B(KW(0), 0);
    WRITE_A(0, p0A, p1A);
    p0A = *(const f32x4*)(gA + KW(64)); p1A = *(const f32x4*)(gA + KW(64) + 4);
    __syncthreads();                     // full drain once (prologue only)

    for (int k0 = 0; k0 < DMODEL; k0 += 128) {
        // even step: compute buf0; stage tile(i+1)->buf1; prefetch A(i+2)
        {
            int ks = KW(k0 + 64);
            int kp = KW(k0 + 128);
            STAGE_B(ks, 1);
            p0B = *(const f32x4*)(gA + kp); p1B = *(const f32x4*)(gA + kp + 4);
            COMPUTE(0);
            WRITE_A(1, p0A, p1A);
            SYNC_PIPE
        }
        // odd step: compute buf1; stage->buf0; prefetch
        {
            int ks = KW(k0 + 128);
            int kp = KW(k0 + 192);
            STAGE_B(ks, 0);
            p0A = *(const f32x4*)(gA + kp); p1A = *(const f32x4*)(gA + kp + 4);
            COMPUTE(1);
            WRITE_A(0, p0B, p1B);
            SYNC_PIPE
        }
    }

    // epilogue: bias; Q pre-scaled by 1/sqrt(128); V written transposed to Vt[b][h][s]
#pragma unroll
    for (int ni = 0; ni < 6; ni++) {
        int col = wn * 96 + ni * 16 + lr;
        int w = col >> 7, h = col & 127;
        const float* bp = (w == 0) ? bq : ((w == 1) ? bk : bv);
        float bias = bp[h];
#pragma unroll
        for (int mi = 0; mi < 2; mi++) {
            int row0 = m0 + wm * 32 + mi * 16 + lq * 4;
            if (w == 2) {
                int b = row0 >> 11, s0 = row0 & (S_LEN - 1);
                bf16x4 pv;
#pragma unroll
                for (int r = 0; r < 4; r++) pv[r] = (short)f2bf(acc[mi][ni][r] + bias);
                *(bf16x4*)(Vt + (size_t)(b * HDIM + h) * S_LEN + s0) = pv;
            } else {
                float scale = (w == 0) ? 0.08838834764831845f : 1.0f;
                u16* dst = (w == 0) ? Qb : Kb;
#pragma unroll
                for (int r = 0; r < 4; r++)
                    dst[(size_t)(row0 + r) * HDIM + h] = f2bf((acc[mi][ni][r] + bias) * scale);
            }
        }
    }
#undef STAGE_B
#undef WRITE_A
#undef COMPUTE
#undef SYNC_PIPE
#undef KW
}

// ---------------- causal flash attention, QBLK=32 per wave (r19) + complement
// pairing (r21, VALIDATED: -7.5us). Wave owns 32 q-rows; block = 4 waves KV-split;
// grid 512 (8 b x 64 qt), blocks bx and bx+256 pair complementary qt (equal per-CU
// work). LDS 65KB -> 2 blocks/CU. launch_bounds(256,2). Defer-max (THR=8) +
// shuffle-free softmax (r15). setprio kept (m191: +4-7% on attn). FROZEN.
__launch_bounds__(256, 2)
__global__ void attn(const u16* __restrict__ Qb, const u16* __restrict__ Kb,
                     const u16* __restrict__ Vt, float* __restrict__ out) {
    __shared__ char lds[66560];          // Om[4][32][128] f32 (65536) + ml[4][32][2] f32 (1024)
    float* Om = (float*)lds;
    float* ml = (float*)(lds + 65536);

    int t = threadIdx.x;
    int wv = t >> 6, l = t & 63, lr = l & 15, lq = l >> 4;
    int bx = blockIdx.x;                 // 512 = 8 b x 64 qt
    int b = bx & 7;                      // batch == XCD for KV L2 locality
    int i = bx >> 3;
    int qt = (i < 32) ? (63 - i) : (i - 32);   // complement pairing
    int qr0 = qt * 32;
    size_t qbase = (size_t)b * S_LEN;
    char* Pw = lds + wv * 16384;         // P tile (32x128B = 4KB) aliases wave's Om region

    bf16x8 aqf[2][4];
#pragma unroll
    for (int mi = 0; mi < 2; mi++)
#pragma unroll
        for (int kk = 0; kk < 4; kk++)
            aqf[mi][kk] = *(const bf16x8*)(Qb + (qbase + qr0 + mi * 16 + lr) * HDIM + kk * 32 + lq * 8);

    f32x4 o_acc[2][8] = {};
    float m_run[2][4], l_run[2][4];
#pragma unroll
    for (int mi = 0; mi < 2; mi++)
#pragma unroll
        for (int r = 0; r < 4; r++) { m_run[mi][r] = -1e38f; l_run[mi][r] = 0.f; }

    int ktd = qt >> 1;                   // diagonal 64-wide tile index
    const u16* Kbase = Kb + qbase * HDIM;
    const u16* Vbase = Vt + (size_t)b * HDIM * S_LEN;

    int cnt = (ktd >= wv) ? (((ktd - wv) >> 2) + 1) : 0;

    for (int j = 0; j < cnt; ++j) {
        int kt = wv + (j << 2);
        int kv0 = kt * 64;

        // S = Q K^T for both 16-row groups; K loaded once per kk serves both
        f32x4 sa[2][4] = {};
#pragma unroll
        for (int kk = 0; kk < 4; kk++) {
            bf16x8 bk8[4];
#pragma unroll
            for (int n = 0; n < 4; n++)
                bk8[n] = *(const bf16x8*)(Kbase + (size_t)(kv0 + n * 16 + lr) * HDIM + kk * 32 + lq * 8);
            __builtin_amdgcn_s_setprio(1);
#pragma unroll
            for (int n = 0; n < 4; n++) {
                sa[0][n] = __builtin_amdgcn_mfma_f32_16x16x32_bf16(aqf[0][kk], bk8[n], sa[0][n], 0, 0, 0);
                sa[1][n] = __builtin_amdgcn_mfma_f32_16x16x32_bf16(aqf[1][kk], bk8[n], sa[1][n], 0, 0, 0);
            }
            __builtin_amdgcn_s_setprio(0);
        }

        if (kt == ktd) {                 // causal mask on the diagonal tile
#pragma unroll
            for (int n = 0; n < 4; n++) {
                int col = kv0 + n * 16 + lr;
#pragma unroll
                for (int mi = 0; mi < 2; mi++)
#pragma unroll
                    for (int r = 0; r < 4; r++) {
                        int row = qr0 + mi * 16 + lq * 4 + r;
                        if (col > row) sa[mi][n][r] = -1e30f;
                    }
            }
        }

        // shuffle-free online softmax (defer-max THR=8), both row groups
#pragma unroll
        for (int mi = 0; mi < 2; mi++) {
#pragma unroll
            for (int r = 0; r < 4; r++) {
                float pmx = fmaxf(fmaxf(sa[mi][0][r], sa[mi][1][r]), fmaxf(sa[mi][2][r], sa[mi][3][r]));
                if (__any(pmx > m_run[mi][r] + 8.0f)) {  // rare, wave-uniform
                    float mx = pmx;
#pragma unroll
                    for (int off = 8; off >= 1; off >>= 1) mx = fmaxf(mx, __shfl_xor(mx, off, 64));
                    float mnew = fmaxf(m_run[mi][r], mx);
                    float f = __expf(m_run[mi][r] - mnew);
                    l_run[mi][r] *= f;
                    m_run[mi][r] = mnew;
#pragma unroll
                    for (int n = 0; n < 8; n++) o_acc[mi][n][r] *= f;
                }
                int prow = mi * 16 + lq * 4 + r;
                char* pb = Pw + prow * 128;
#pragma unroll
                for (int n = 0; n < 4; n++) {
                    float e = __expf(sa[mi][n][r] - m_run[mi][r]);
                    l_run[mi][r] += e;               // per-lane partial, no shuffles
                    int col = n * 16 + lr;
                    *(u16*)(pb + (((col >> 3) ^ (prow & 7)) << 4) + (col & 7) * 2) = f2bf(e);
                }
            }
        }

        // O += P V : V loaded once per n serves both row groups
#pragma unroll
        for (int kk = 0; kk < 2; kk++) {
            int slot = kk * 4 + lq;
            int row0 = lr, row1 = 16 + lr;
            bf16x8 pa0 = *(bf16x8*)(Pw + row0 * 128 + ((slot ^ (row0 & 7)) << 4));
            bf16x8 pa1 = *(bf16x8*)(Pw + row1 * 128 + ((slot ^ (row1 & 7)) << 4));
            __builtin_amdgcn_s_setprio(1);
#pragma unroll
            for (int n = 0; n < 8; n++) {
                bf16x8 vb8 = *(const bf16x8*)(Vbase + (size_t)(n * 16 + lr) * S_LEN + kv0 + kk * 32 + lq * 8);
                o_acc[0][n] = __builtin_amdgcn_mfma_f32_16x16x32_bf16(pa0, vb8, o_acc[0][n], 0, 0, 0);
                o_acc[1][n] = __builtin_amdgcn_mfma_f32_16x16x32_bf16(pa1, vb8, o_acc[1][n], 0, 0, 0);
            }
            __builtin_amdgcn_s_setprio(0);
        }
    }

    // fold the per-lane l partials into group sums (once, not per tile)
#pragma unroll
    for (int mi = 0; mi < 2; mi++)
#pragma unroll
        for (int r = 0; r < 4; r++) {
#pragma unroll
            for (int off = 8; off >= 1; off >>= 1)
                l_run[mi][r] += __shfl_xor(l_run[mi][r], off, 64);
        }

    // write partials (Om[wv] overwrites this wave's P area only after its last P read)
    __builtin_amdgcn_sched_barrier(0);
#pragma unroll
    for (int mi = 0; mi < 2; mi++)
#pragma unroll
        for (int n = 0; n < 8; n++)
#pragma unroll
            for (int r = 0; r < 4; r++)
                Om[wv * 4096 + (mi * 16 + lq * 4 + r) * 128 + n * 16 + lr] = o_acc[mi][n][r];
    if (lr == 0) {
#pragma unroll
        for (int mi = 0; mi < 2; mi++)
#pragma unroll
            for (int r = 0; r < 4; r++) {
                int row = mi * 16 + lq * 4 + r;
                ml[wv * 64 + row * 2 + 0] = m_run[mi][r];
                ml[wv * 64 + row * 2 + 1] = l_run[mi][r];
            }
    }
    __syncthreads();

    // merge the 4 partials: thread -> (row = t>>3 in 0..31, cols (t&7)*16 .. +16)
    {
        int row = t >> 3, c0 = (t & 7) * 16;
        float m4[4], l4[4];
#pragma unroll
        for (int w = 0; w < 4; w++) {
            m4[w] = ml[w * 64 + row * 2 + 0];
            l4[w] = ml[w * 64 + row * 2 + 1];
        }
        float ms = fmaxf(fmaxf(m4[0], m4[1]), fmaxf(m4[2], m4[3]));
        float wt[4], ls = 0.f;
#pragma unroll
        for (int w = 0; w < 4; w++) { wt[w] = __expf(m4[w] - ms); ls += l4[w] * wt[w]; }
        float inv = 1.0f / ls;
        f32x4 r0 = (f32x4)0.f, r1 = (f32x4)0.f, r2 = (f32x4)0.f, r3 = (f32x4)0.f;
#pragma unroll
        for (int w = 0; w < 4; w++) {
            const f32x4* Op = (const f32x4*)(Om + w * 4096 + row * 128 + c0);
            r0 += Op[0] * wt[w];
            r1 += Op[1] * wt[w];
            r2 += Op[2] * wt[w];
            r3 += Op[3] * wt[w];
        }
        f32x4* dst = (f32x4*)(out + (qbase + qr0 + row) * HDIM + c0);
        dst[0] = r0 * inv;
        dst[1] = r1 * inv;
        dst[2] = r2 * inv;
        dst[3] = r3 * inv;
    }
}

extern "C" void kernel_launch(void* const* d_in, const int* in_sizes, int n_in,
                              void* d_out, int out_size, void* d_ws, size_t ws_size,
                              hipStream_t stream) {
    const float* hs = (const float*)d_in[0];
    const float* Wq = (const float*)d_in[1];
    const float* bq = (const float*)d_in[2];
    const float* Wk = (const float*)d_in[3];
    const float* bk = (const float*)d_in[4];
    const float* Wv = (const float*)d_in[5];
    const float* bv = (const float*)d_in[6];
    float* out = (float*)d_out;

    char* ws = (char*)d_ws;
    u16* Qb = (u16*)(ws);                       // 4 MB  [16384][128] bf16 (pre-scaled)
    u16* Kb = (u16*)(ws + (size_t)(4  << 20));  // 4 MB
    u16* Vt = (u16*)(ws + (size_t)(8  << 20));  // 4 MB  [8][128][2048] (written by qkv epilogue)
    u16* Wp = (u16*)(ws + (size_t)(12 << 20));  // 1.5 MB [384][2048]

    hipLaunchKernelGGL(pack_weights, dim3(192), dim3(256), 0, stream, Wq, Wk, Wv, Wp);
    hipLaunchKernelGGL(qkv_gemm, dim3(256), dim3(512), 0, stream, hs, Wp, bq, bk, bv, Qb, Kb, Vt);
    hipLaunchKernelGGL(attn, dim3(512), dim3(256), 0, stream, Qb, Kb, Vt, out);
}